// Round 6
// baseline (544.383 us; speedup 1.0000x reference)
//
#include <hip/hip_runtime.h>
#include <stdint.h>

// Pipeline:
// img (8,160,240,3) -> conv1 6x6 (+fused 2x2 pool) -> (8,77,117,32)
// -> conv2 3x3 (+fused 2x2 pool) -> (8,37,57,64)
// -> conv3 3x3 -> (8,35,55,128) -> flatten 246400 -> dense 256 -> dense 38400
// -> transform -> pred (8,40,60,16); NMS -> keep (8,3,4800)

static __device__ __forceinline__ float sigmoidf_(float x) {
  return 1.0f / (1.0f + expf(-x));
}

// ---------------- conv1 6x6x3->32 + fused 2x2 maxpool ----------------
__global__ __launch_bounds__(256) void k_conv1p(const float* __restrict__ in,
    const float* __restrict__ w, const float* __restrict__ bias, float* __restrict__ out) {
  __shared__ float s_in[21 * 37 * 3];    // [y][x][c]
  __shared__ float s_w[6 * 6 * 3 * 32];  // [ky][kx][c][o]
  int tx = blockIdx.x, ty = blockIdx.y, n = blockIdx.z;
  int tid = threadIdx.x;
  int iy0 = ty * 16, ix0 = tx * 32;
  for (int idx = tid; idx < 3456; idx += 256) s_w[idx] = w[idx];
  for (int idx = tid; idx < 21 * 37 * 3; idx += 256) {
    int c = idx % 3;
    int rem = idx / 3;
    int x = rem % 37, y = rem / 37;
    int gy = iy0 + y, gx = ix0 + x;
    float v = 0.f;
    if (gy < 160 && gx < 240) v = in[((size_t)(n * 160 + gy) * 240 + gx) * 3 + c];
    s_in[idx] = v;
  }
  __syncthreads();

  int cg = tid >> 6;
  int l = tid & 63;
  int py = l >> 2;
  int px0 = (l & 3) * 8;

  float acc[8][8];
  float bj[8];
#pragma unroll
  for (int j = 0; j < 8; j++) bj[j] = bias[cg * 8 + j];
#pragma unroll
  for (int k = 0; k < 8; k++)
#pragma unroll
    for (int j = 0; j < 8; j++) acc[k][j] = bj[j];

#pragma unroll 1
  for (int ky = 0; ky < 6; ky++) {
#pragma unroll 1
    for (int kx = 0; kx < 6; kx++) {
#pragma unroll 1
      for (int c = 0; c < 3; c++) {
        const float* ib = s_in + ((py + ky) * 37 + px0 + kx) * 3 + c;
        float iv[8];
#pragma unroll
        for (int k = 0; k < 8; k++) iv[k] = ib[k * 3];
        const float* wb = s_w + ((ky * 6 + kx) * 3 + c) * 32 + cg * 8;
        float wv[8];
#pragma unroll
        for (int j = 0; j < 8; j++) wv[j] = wb[j];
#pragma unroll
        for (int k = 0; k < 8; k++)
#pragma unroll
          for (int j = 0; j < 8; j++) acc[k][j] = fmaf(iv[k], wv[j], acc[k][j]);
      }
    }
  }
  float pm[4][8];
#pragma unroll
  for (int kk = 0; kk < 4; kk++)
#pragma unroll
    for (int j = 0; j < 8; j++) pm[kk][j] = fmaxf(acc[2 * kk][j], acc[2 * kk + 1][j]);
#pragma unroll
  for (int kk = 0; kk < 4; kk++)
#pragma unroll
    for (int j = 0; j < 8; j++) {
      float o = __shfl_down(pm[kk][j], 4);
      pm[kk][j] = fmaxf(pm[kk][j], o);
    }
  if (!(py & 1)) {
    int pyp = ty * 8 + (py >> 1);
    if (pyp < 77) {
#pragma unroll
      for (int kk = 0; kk < 4; kk++) {
        int pxp = tx * 16 + (l & 3) * 4 + kk;
        if (pxp < 117) {
          float* op = out + ((size_t)(n * 77 + pyp) * 117 + pxp) * 32 + cg * 8;
          float4 v0, v1;
          v0.x = fmaxf(pm[kk][0], 0.f); v0.y = fmaxf(pm[kk][1], 0.f);
          v0.z = fmaxf(pm[kk][2], 0.f); v0.w = fmaxf(pm[kk][3], 0.f);
          v1.x = fmaxf(pm[kk][4], 0.f); v1.y = fmaxf(pm[kk][5], 0.f);
          v1.z = fmaxf(pm[kk][6], 0.f); v1.w = fmaxf(pm[kk][7], 0.f);
          ((float4*)op)[0] = v0;
          ((float4*)op)[1] = v1;
        }
      }
    }
  }
}

// ---------------- conv2 3x3x32->64 + fused 2x2 maxpool ----------------
__global__ __launch_bounds__(128) void k_conv2p(const float* __restrict__ in,
    const float* __restrict__ w, const float* __restrict__ bias, float* __restrict__ out) {
  __shared__ float s_in[32 * 10 * 18];  // [c][y][x]
  int tx = blockIdx.x, ty = blockIdx.y, n = blockIdx.z;
  int tid = threadIdx.x;
  int iy0 = ty * 8, ix0 = tx * 16;
  for (int idx = tid; idx < 10 * 18 * 32; idx += 128) {
    int c = idx & 31;
    int rem = idx >> 5;
    int x = rem % 18, y = rem / 18;
    int gy = iy0 + y, gx = ix0 + x;
    float v = 0.f;
    if (gy < 77 && gx < 117) v = in[((size_t)(n * 77 + gy) * 117 + gx) * 32 + c];
    s_in[c * 180 + y * 18 + x] = v;
  }
  __syncthreads();

  int cg = tid >> 4;
  int pg = tid & 15;
  int py = pg >> 1;
  int px0 = (pg & 1) * 8;

  float acc[8][8];
  float bj[8];
#pragma unroll
  for (int j = 0; j < 8; j++) bj[j] = bias[cg * 8 + j];
#pragma unroll
  for (int k = 0; k < 8; k++)
#pragma unroll
    for (int j = 0; j < 8; j++) acc[k][j] = bj[j];

#pragma unroll 1
  for (int ky = 0; ky < 3; ky++) {
#pragma unroll 1
    for (int kx = 0; kx < 3; kx++) {
      const float* wbase = w + (size_t)((ky * 3 + kx) * 32) * 64 + cg * 8;
      const float* ibase = s_in + (py + ky) * 18 + px0 + kx;
#pragma unroll 4
      for (int c = 0; c < 32; c++) {
        float4 wa = *(const float4*)(wbase + (size_t)c * 64);
        float4 wb = *(const float4*)(wbase + (size_t)c * 64 + 4);
        const float* ib = ibase + c * 180;
        float iv[8];
#pragma unroll
        for (int k = 0; k < 8; k++) iv[k] = ib[k];
#pragma unroll
        for (int k = 0; k < 8; k++) {
          acc[k][0] = fmaf(iv[k], wa.x, acc[k][0]);
          acc[k][1] = fmaf(iv[k], wa.y, acc[k][1]);
          acc[k][2] = fmaf(iv[k], wa.z, acc[k][2]);
          acc[k][3] = fmaf(iv[k], wa.w, acc[k][3]);
          acc[k][4] = fmaf(iv[k], wb.x, acc[k][4]);
          acc[k][5] = fmaf(iv[k], wb.y, acc[k][5]);
          acc[k][6] = fmaf(iv[k], wb.z, acc[k][6]);
          acc[k][7] = fmaf(iv[k], wb.w, acc[k][7]);
        }
      }
    }
  }
  float pm[4][8];
#pragma unroll
  for (int kk = 0; kk < 4; kk++)
#pragma unroll
    for (int j = 0; j < 8; j++) pm[kk][j] = fmaxf(acc[2 * kk][j], acc[2 * kk + 1][j]);
#pragma unroll
  for (int kk = 0; kk < 4; kk++)
#pragma unroll
    for (int j = 0; j < 8; j++) {
      float o = __shfl_down(pm[kk][j], 2);
      pm[kk][j] = fmaxf(pm[kk][j], o);
    }
  if (!(pg & 2)) {
    int pyp = ty * 4 + (py >> 1);
    if (pyp < 37) {
#pragma unroll
      for (int kk = 0; kk < 4; kk++) {
        int pxp = tx * 8 + (pg & 1) * 4 + kk;
        if (pxp < 57) {
          float* op = out + ((size_t)(n * 37 + pyp) * 57 + pxp) * 64 + cg * 8;
          float4 v0, v1;
          v0.x = fmaxf(pm[kk][0], 0.f); v0.y = fmaxf(pm[kk][1], 0.f);
          v0.z = fmaxf(pm[kk][2], 0.f); v0.w = fmaxf(pm[kk][3], 0.f);
          v1.x = fmaxf(pm[kk][4], 0.f); v1.y = fmaxf(pm[kk][5], 0.f);
          v1.z = fmaxf(pm[kk][6], 0.f); v1.w = fmaxf(pm[kk][7], 0.f);
          ((float4*)op)[0] = v0;
          ((float4*)op)[1] = v1;
        }
      }
    }
  }
}

// ---------------- conv3: 3x3x64 -> 128, channel-split x2 ----------------
__global__ __launch_bounds__(256) void k_conv3(const float* __restrict__ in,
    const float* __restrict__ w, const float* __restrict__ bias, float* __restrict__ out) {
  __shared__ float s_in[64 * 10 * 18];  // [c][y][x]
  int tx = blockIdx.x, ty = blockIdx.y, z = blockIdx.z;
  int n = z >> 1, h = z & 1;
  int tid = threadIdx.x;
  int iy0 = ty * 8, ix0 = tx * 16;
  for (int idx = tid; idx < 10 * 18 * 64; idx += 256) {
    int c = idx & 63;
    int rem = idx >> 6;
    int x = rem % 18, y = rem / 18;
    int gy = iy0 + y, gx = ix0 + x;
    float v = 0.f;
    if (gy < 37 && gx < 57) v = in[((size_t)(n * 37 + gy) * 57 + gx) * 64 + c];
    s_in[c * 180 + y * 18 + x] = v;
  }
  __syncthreads();

  int cg = tid >> 4;
  int pg = tid & 15;
  int py = pg >> 1;
  int px0 = (pg & 1) * 8;
  int ob = h * 64 + cg * 4;

  float acc[8][4];
  float bj[4];
#pragma unroll
  for (int j = 0; j < 4; j++) bj[j] = bias[ob + j];
#pragma unroll
  for (int k = 0; k < 8; k++)
#pragma unroll
    for (int j = 0; j < 4; j++) acc[k][j] = bj[j];

#pragma unroll 1
  for (int ky = 0; ky < 3; ky++) {
#pragma unroll 1
    for (int kx = 0; kx < 3; kx++) {
      const float* wbase = w + (size_t)((ky * 3 + kx) * 64) * 128 + ob;
      const float* ibase = s_in + (py + ky) * 18 + px0 + kx;
#pragma unroll 4
      for (int c = 0; c < 64; c++) {
        float4 wa = *(const float4*)(wbase + (size_t)c * 128);
        const float* ib = ibase + c * 180;
        float iv[8];
#pragma unroll
        for (int k = 0; k < 8; k++) iv[k] = ib[k];
#pragma unroll
        for (int k = 0; k < 8; k++) {
          acc[k][0] = fmaf(iv[k], wa.x, acc[k][0]);
          acc[k][1] = fmaf(iv[k], wa.y, acc[k][1]);
          acc[k][2] = fmaf(iv[k], wa.z, acc[k][2]);
          acc[k][3] = fmaf(iv[k], wa.w, acc[k][3]);
        }
      }
    }
  }
  int oy = iy0 + py;
  if (oy < 35) {
#pragma unroll
    for (int k = 0; k < 8; k++) {
      int ox = ix0 + px0 + k;
      if (ox < 55) {
        float* op = out + ((size_t)(n * 35 + oy) * 55 + ox) * 128 + ob;
        float4 v0;
        v0.x = fmaxf(acc[k][0], 0.f); v0.y = fmaxf(acc[k][1], 0.f);
        v0.z = fmaxf(acc[k][2], 0.f); v0.w = fmaxf(acc[k][3], 0.f);
        ((float4*)op)[0] = v0;
      }
    }
  }
}

// ---------------- dense1: (8,246400) @ (246400,256), split-K partials ----------------
// reads a3 (n-major) directly: x[n][row] = a3[n*246400 + row]  (no transpose kernel)
__global__ __launch_bounds__(256) void k_dense1(const float* __restrict__ a3,
    const float* __restrict__ wd1, float* __restrict__ part) {
  __shared__ float red[4][64][32];
  int c = blockIdx.x;
  int tid = threadIdx.x;
  int c4 = tid & 63;
  int ks = tid >> 6;
  int k0 = c * 256;
  int kn = 246400 - k0;
  if (kn > 256) kn = 256;
  float acc[8][4];
#pragma unroll
  for (int n = 0; n < 8; n++)
#pragma unroll
    for (int j = 0; j < 4; j++) acc[n][j] = 0.f;
  int kbeg = ks * 64;
  int kend = kbeg + 64;
  if (kend > kn) kend = kn;
#pragma unroll 1
  for (int kk = kbeg; kk < kend; kk++) {
    size_t row = (size_t)(k0 + kk);
    float4 wv = *(const float4*)(wd1 + row * 256 + c4 * 4);
    float xs[8];
#pragma unroll
    for (int n = 0; n < 8; n++) xs[n] = a3[(size_t)n * 246400 + row];
#pragma unroll
    for (int n = 0; n < 8; n++) {
      acc[n][0] = fmaf(xs[n], wv.x, acc[n][0]);
      acc[n][1] = fmaf(xs[n], wv.y, acc[n][1]);
      acc[n][2] = fmaf(xs[n], wv.z, acc[n][2]);
      acc[n][3] = fmaf(xs[n], wv.w, acc[n][3]);
    }
  }
#pragma unroll
  for (int n = 0; n < 8; n++)
#pragma unroll
    for (int j = 0; j < 4; j++) red[ks][c4][n * 4 + j] = acc[n][j];
  __syncthreads();
  for (int o = tid; o < 2048; o += 256) {
    int col = o & 255, n = o >> 8;
    int cc = col >> 2, j = col & 3;
    float s = red[0][cc][n * 4 + j] + red[1][cc][n * 4 + j] +
              red[2][cc][n * 4 + j] + red[3][cc][n * 4 + j];
    part[(size_t)c * 2048 + n * 256 + col] = s;
  }
}

// ---------------- reduce1 stage A: 16 c-chunks x 2048 outputs, coalesced ----------------
__global__ __launch_bounds__(256) void k_reduce1a(const float* __restrict__ part,
    float* __restrict__ partr) {
  int bx = blockIdx.x;                       // 0..15 c-chunk
  int t = blockIdx.y * 256 + threadIdx.x;    // 0..2047
  int cbeg = bx * 61;
  int cend = cbeg + 61;
  if (cend > 963) cend = 963;
  float s = 0.f;
  for (int c = cbeg; c < cend; c++) s += part[(size_t)c * 2048 + t];
  partr[(size_t)bx * 2048 + t] = s;
}

__global__ __launch_bounds__(256) void k_reduce1b(const float* __restrict__ partr,
    const float* __restrict__ bd1, float* __restrict__ d1t) {
  int t = blockIdx.x * 256 + threadIdx.x;
  if (t >= 2048) return;
  float s = 0.f;
#pragma unroll
  for (int b = 0; b < 16; b++) s += partr[(size_t)b * 2048 + t];
  int n = t >> 8, j = t & 255;
  float v = s + bd1[j];
  d1t[j * 8 + n] = fmaxf(v, 0.f);  // ReLU; store transposed (256,8)
}

// ---------------- dense2 full-K fused: (8,256) @ (256,38400) + bias ----------------
__global__ __launch_bounds__(256) void k_dense2f(const float* __restrict__ d1t,
    const float* __restrict__ wd2, const float* __restrict__ bd2, float* __restrict__ d2) {
  __shared__ float red[4][64][32];
  int jb = blockIdx.x;  // 150
  int tid = threadIdx.x;
  int c4 = tid & 63;
  int ks = tid >> 6;
  int j0 = jb * 256 + c4 * 4;
  float acc[8][4];
#pragma unroll
  for (int n = 0; n < 8; n++)
#pragma unroll
    for (int j = 0; j < 4; j++) acc[n][j] = 0.f;
#pragma unroll 1
  for (int kk = 0; kk < 64; kk++) {
    int row = ks * 64 + kk;
    float4 wv = *(const float4*)(wd2 + (size_t)row * 38400 + j0);
    float4 xa = *(const float4*)(d1t + row * 8);
    float4 xb = *(const float4*)(d1t + row * 8 + 4);
    float xs[8] = {xa.x, xa.y, xa.z, xa.w, xb.x, xb.y, xb.z, xb.w};
#pragma unroll
    for (int n = 0; n < 8; n++) {
      acc[n][0] = fmaf(xs[n], wv.x, acc[n][0]);
      acc[n][1] = fmaf(xs[n], wv.y, acc[n][1]);
      acc[n][2] = fmaf(xs[n], wv.z, acc[n][2]);
      acc[n][3] = fmaf(xs[n], wv.w, acc[n][3]);
    }
  }
#pragma unroll
  for (int n = 0; n < 8; n++)
#pragma unroll
    for (int j = 0; j < 4; j++) red[ks][c4][n * 4 + j] = acc[n][j];
  __syncthreads();
  for (int o = tid; o < 2048; o += 256) {
    int col = o & 255, n = o >> 8;
    int cc = col >> 2, j = col & 3;
    float s = red[0][cc][n * 4 + j] + red[1][cc][n * 4 + j] +
              red[2][cc][n * 4 + j] + red[3][cc][n * 4 + j] + bd2[jb * 256 + col];
    d2[(size_t)n * 38400 + jb * 256 + col] = s;
  }
}

// ---------------- transform + keep-zero fused ----------------
__global__ __launch_bounds__(256) void k_transform(const float* __restrict__ d2,
    float* __restrict__ pred, float* __restrict__ boxd, float* __restrict__ keep_out) {
  int t = blockIdx.x * 256 + threadIdx.x;  // 0..115199
  if (t < 115200) keep_out[t] = 0.f;
  if (t >= 19200) return;
  int cell = t % 2400;
  int n = t / 2400;
  float gx = (float)(cell % 60), gy = (float)(cell / 60);
  const float* p = d2 + (size_t)t * 16;
  float o[16];
  o[0] = (sigmoidf_(p[0]) + gx) * 4.0f;
  o[1] = (sigmoidf_(p[1]) + gy) * 4.0f;
  o[2] = expf(p[2]) * 60.0f * 4.0f;
  o[3] = expf(p[3]) * 30.0f * 4.0f;
  o[4] = sigmoidf_(p[4]);
  o[5] = sigmoidf_(p[5]);
  o[6] = sigmoidf_(p[6]);
  o[7] = sigmoidf_(p[7]);
  o[8] = (p[8] + gx) * 4.0f;
  o[9] = (p[9] + gy) * 4.0f;
  o[10] = expf(p[10]) * 20.0f * 4.0f;
  o[11] = expf(p[11]) * 40.0f * 4.0f;
  o[12] = p[12];
  o[13] = sigmoidf_(p[13]);
  o[14] = sigmoidf_(p[14]);
  o[15] = sigmoidf_(p[15]);
  float* op = pred + (size_t)t * 16;
#pragma unroll
  for (int q = 0; q < 16; q++) op[q] = o[q];
#pragma unroll
  for (int h = 0; h < 2; h++) {
    int b = n * 4800 + h * 2400 + cell;
    float X = o[h * 8 + 0], Y = o[h * 8 + 1], W = o[h * 8 + 2], H = o[h * 8 + 3];
    float conf = o[h * 8 + 4];
    float c0 = o[h * 8 + 5], c1 = o[h * 8 + 6], c2 = o[h * 8 + 7];
    int cls = 0; float best = c0;
    if (c1 > best) { best = c1; cls = 1; }
    if (c2 > best) { best = c2; cls = 2; }
    float x1 = X - W / 2.0f, y1 = Y - H / 2.0f;
    float x2 = X + W / 2.0f, y2 = Y + H / 2.0f;
    float area = (x2 - x1 + 1.0f) * (y2 - y1 + 1.0f);
    float* bp2 = boxd + (size_t)b * 8;
    bp2[0] = x1; bp2[1] = y1; bp2[2] = x2; bp2[3] = y2;
    bp2[4] = area; bp2[5] = conf;
    ((int*)bp2)[6] = cls; bp2[7] = 0.f;
  }
}

// ---------------- NMS: one block per (image, class), LDS-resident ----------------
// Phases 1-2 (256 thr): compact + bitonic sort + stage boxes + avail bitmask.
// Phase 3 (wave 0 only, barrier-free): greedy scan; per kept box, each lane
// computes one IoU per 64-col chunk and __ballot yields the suppression word.
__global__ __launch_bounds__(256) void k_nms(const float* __restrict__ boxd,
    float* __restrict__ keep_out) {
  __shared__ unsigned long long key[8192];  // sort keys; low32 = orig idx
  __shared__ float4 sbox[4800];             // sorted x1,y1,x2,y2
  __shared__ unsigned long long avail[75];  // availability over sorted idx
  __shared__ int scnt;
  int bid = blockIdx.x;  // 0..23
  int n = bid / 3, c = bid - n * 3;
  int tid = threadIdx.x;
  const float* bd = boxd + (size_t)n * 4800 * 8;
  if (tid == 0) scnt = 0;
  __syncthreads();

  // ---- compact ----
  for (int p = tid; p < 4800; p += 256) {
    const float* bp = bd + (size_t)p * 8;
    float conf = bp[5];
    int cls = ((const int*)bp)[6];
    if (conf > 0.5f && cls == c) {
      int slot = atomicAdd(&scnt, 1);
      unsigned u = __float_as_uint(conf);
      unsigned asc = (u & 0x80000000u) ? ~u : (u | 0x80000000u);
      key[slot] = (((unsigned long long)(~asc)) << 32) | (unsigned)p;
    }
  }
  __syncthreads();
  int V = scnt;
  if (V == 0) return;
  int Vp2 = 1;
  while (Vp2 < V) Vp2 <<= 1;
  for (int s = V + tid; s < Vp2; s += 256) key[s] = ~0ull;

  // ---- bitonic sort ascending -> score desc, idx asc (stable argsort(-score)) ----
  for (int k = 2; k <= Vp2; k <<= 1) {
    for (int j = k >> 1; j > 0; j >>= 1) {
      __syncthreads();
      int jm = j - 1;
      for (int t2 = tid; t2 < (Vp2 >> 1); t2 += 256) {
        int i = ((t2 & ~jm) << 1) | (t2 & jm);
        int q = i | j;
        bool up = ((i & k) == 0);
        unsigned long long a = key[i], b2 = key[q];
        if ((a > b2) == up) { key[i] = b2; key[q] = a; }
      }
    }
  }
  __syncthreads();

  // ---- stage sorted boxes + init availability ----
  for (int s = tid; s < V; s += 256) {
    unsigned p = (unsigned)(key[s] & 0xFFFFFFFFull);
    const float* bp = bd + (size_t)p * 8;
    float4 b4;
    b4.x = bp[0]; b4.y = bp[1]; b4.z = bp[2]; b4.w = bp[3];
    sbox[s] = b4;
  }
  for (int w = tid; w < 75; w += 256) {
    int rem = V - (w << 6);
    avail[w] = (rem >= 64) ? ~0ull : (rem <= 0 ? 0ull : ((1ull << rem) - 1ull));
  }
  __syncthreads();

  // ---- greedy, single wave, barrier-free ----
  if (tid >= 64) return;
  int l = tid;
  int wlast = (V - 1) >> 6;
  float* ko = keep_out + (size_t)bid * 4800;
  for (;;) {
    // find min available sorted index: lane l owns words l and 64+l
    int cand = 0x7FFFFFFF;
    unsigned long long a0 = avail[l];
    if (a0) cand = (l << 6) + __ffsll((long long)a0) - 1;
    if (l < 11) {
      unsigned long long a1 = avail[64 + l];
      if (a1) {
        int c2 = ((64 + l) << 6) + __ffsll((long long)a1) - 1;
        if (c2 < cand) cand = c2;
      }
    }
#pragma unroll
    for (int off = 32; off > 0; off >>= 1) {
      int o = __shfl_xor(cand, off, 64);
      if (o < cand) cand = o;
    }
    if (cand == 0x7FFFFFFF) break;
    int i = cand;
    int tw = i >> 6;
    if (l == 0) {
      ko[(unsigned)(key[i] & 0xFFFFFFFFull)] = 1.0f;
      avail[tw] &= ~(1ull << (i & 63));  // clear box i (wave-ordered before reads below)
    }
    float4 bi = sbox[i];  // uniform -> LDS broadcast
    float ai = (bi.z - bi.x + 1.0f) * (bi.w - bi.y + 1.0f);
    for (int w = tw; w <= wlast; w++) {
      unsigned long long aw = avail[w];  // uniform read
      if (!aw) continue;
      int col = (w << 6) + l;
      float4 bj = sbox[col];
      float iw = fminf(bi.z, bj.z) - fmaxf(bi.x, bj.x) + 1.0f;
      float ih = fminf(bi.w, bj.w) - fmaxf(bi.y, bj.y) + 1.0f;
      iw = fmaxf(iw, 0.f);
      ih = fmaxf(ih, 0.f);
      float inter = iw * ih;
      float aj = (bj.z - bj.x + 1.0f) * (bj.w - bj.y + 1.0f);
      float iou = inter / (ai + aj - inter);
      bool pr = (col > i) && (col < V) && (iou >= 0.4f);
      unsigned long long word = __ballot(pr);
      if (word && l == 0) avail[w] = aw & ~word;
    }
  }
}

extern "C" void kernel_launch(void* const* d_in, const int* in_sizes, int n_in,
                              void* d_out, int out_size, void* d_ws, size_t ws_size,
                              hipStream_t stream) {
  const float* img = (const float*)d_in[0];
  const float* w1 = (const float*)d_in[1];
  const float* b1 = (const float*)d_in[2];
  const float* w2 = (const float*)d_in[3];
  const float* b2 = (const float*)d_in[4];
  const float* w3 = (const float*)d_in[5];
  const float* b3 = (const float*)d_in[6];
  const float* wd1 = (const float*)d_in[7];
  const float* bd1 = (const float*)d_in[8];
  const float* wd2 = (const float*)d_in[9];
  const float* bd2 = (const float*)d_in[10];

  float* ws = (float*)d_ws;
  float* a3 = ws + 0;                 // 1,971,200
  float* pd1 = ws + 3942400;          // 963*2048 = 1,972,224
  float* partr = ws + 5914624;        // 16*2048 = 32,768
  float* d1t = ws + 5947392;          // 2048
  float* d2 = ws + 5949440;           // 307,200
  float* boxd = ws + 6256640;         // 307,200
  float* p1 = ws + 9324800;           // 8*77*117*32 = 2,306,304 pooled conv1
  float* p2 = ws + 16047104;          // 8*37*57*64 = 1,079,808 pooled conv2

  float* pred = (float*)d_out;
  float* keep = pred + 307200;

  k_conv1p<<<dim3(8, 10, 8), 256, 0, stream>>>(img, w1, b1, p1);
  k_conv2p<<<dim3(8, 10, 8), 128, 0, stream>>>(p1, w2, b2, p2);
  k_conv3<<<dim3(4, 5, 16), 256, 0, stream>>>(p2, w3, b3, a3);
  k_dense1<<<963, 256, 0, stream>>>(a3, wd1, pd1);
  k_reduce1a<<<dim3(16, 8), 256, 0, stream>>>(pd1, partr);
  k_reduce1b<<<8, 256, 0, stream>>>(partr, bd1, d1t);
  k_dense2f<<<150, 256, 0, stream>>>(d1t, wd2, bd2, d2);
  k_transform<<<450, 256, 0, stream>>>(d2, pred, boxd, keep);
  k_nms<<<24, 256, 0, stream>>>(boxd, keep);
}